// Round 4
// baseline (1305.335 us; speedup 1.0000x reference)
//
#include <hip/hip_runtime.h>
#include <hip/hip_bf16.h>
#include <cstdint>

// B=16384, L=5, D=1024.  M = 81920 rows.
// scores = x^T (Wq^T Wk) x  ->  Gt[n,k]; u = x@Gt^T; s = rowdot(u,x)/32.
// Pipeline:
//   k_cvt_bf16: x->xb ; Wv->Bcat[1024:2048] ; W1->W1b ; W2->W2b
//   k_gt:       Gt -> Bcat[0:1024]
//   k_gemm256<0>: [u|v] = xb @ Bcat^T  -> d_out as bf16 [M][2048]
//   k_attn_ln:  scores->softmax->attn, y = LN(attn+x) -> xb in place
//   k_gemm256<1>: h = GELU(y @ W1^T + b1) -> hb
//   k_gemm256<3>: z = h @ W2^T + b2 + y -> zb bf16 (ws)
//   k_ln_final_bf: LN(z)*ff_g+ff_b -> d_out fp32
//
// GEMM: 256x256 tile, BK=32, ring-4 LDS slots (128 KiB), read-ahead frag
// pipeline: per K-tile issue ds_reads for t+1 (ping-pong regs) + stage t+3
// BEFORE the 32 MFMAs on tile t -> compiler emits counted lgkmcnt(12), LDS
// reads drain under MFMA. One counted vmcnt(4)+barrier per tile (never 0
// in-loop). No swizzle needed: 64-B LDS rows give uniform 8-req/bank b128.

typedef float f32x4 __attribute__((ext_vector_type(4)));
typedef __bf16 bf16x8 __attribute__((ext_vector_type(8)));

#define DD 1024
#define NROWS 81920L

__device__ __forceinline__ unsigned short f2bf(float f) {
  union { float f; unsigned u; } c; c.f = f;
  unsigned u = c.u;
  return (unsigned short)((u + 0x7FFFu + ((u >> 16) & 1u)) >> 16);  // RNE
}
__device__ __forceinline__ float bf2f(unsigned short b) {
  union { unsigned u; float f; } c; c.u = ((unsigned)b) << 16;
  return c.f;
}
__device__ __forceinline__ void unpack8(uint4 v, float* o) {
  o[0] = bf2f((unsigned short)(v.x & 0xffffu)); o[1] = bf2f((unsigned short)(v.x >> 16));
  o[2] = bf2f((unsigned short)(v.y & 0xffffu)); o[3] = bf2f((unsigned short)(v.y >> 16));
  o[4] = bf2f((unsigned short)(v.z & 0xffffu)); o[5] = bf2f((unsigned short)(v.z >> 16));
  o[6] = bf2f((unsigned short)(v.w & 0xffffu)); o[7] = bf2f((unsigned short)(v.w >> 16));
}
__device__ __forceinline__ void gload_lds16(const void* g, void* l) {
  __builtin_amdgcn_global_load_lds(
      (const __attribute__((address_space(1))) unsigned int*)g,
      (__attribute__((address_space(3))) unsigned int*)l, 16, 0, 0);
}

// ---------------- fp32 -> bf16 ----------------
__global__ void __launch_bounds__(256) k_cvt_bf16(const float* __restrict__ in,
                                                  unsigned short* __restrict__ out, long n) {
  long i = ((long)blockIdx.x * blockDim.x + threadIdx.x) * 8;
  long stride = (long)gridDim.x * blockDim.x * 8;
  for (; i < n; i += stride) {
    f32x4 a = *(const f32x4*)(in + i);
    f32x4 b = *(const f32x4*)(in + i + 4);
    uint4 o;
    o.x = (unsigned)f2bf(a[0]) | ((unsigned)f2bf(a[1]) << 16);
    o.y = (unsigned)f2bf(a[2]) | ((unsigned)f2bf(a[3]) << 16);
    o.z = (unsigned)f2bf(b[0]) | ((unsigned)f2bf(b[1]) << 16);
    o.w = (unsigned)f2bf(b[2]) | ((unsigned)f2bf(b[3]) << 16);
    *(uint4*)(out + i) = o;
  }
}

// ---------------- Gt[n,k] = sum_e Wk[e,n] * Wq[e,k] ----------------
__global__ void __launch_bounds__(256) k_gt(const float* __restrict__ Wq,
                                            const float* __restrict__ Wk,
                                            unsigned short* __restrict__ Gt) {
  __shared__ float sk[16][16];
  __shared__ float sq[16][64];
  const int tx = threadIdx.x, ty = threadIdx.y;
  const int n0 = blockIdx.y * 16;
  const int k0 = blockIdx.x * 64;
  float acc[4] = {0.f, 0.f, 0.f, 0.f};
  for (int e0 = 0; e0 < 1024; e0 += 16) {
    sk[ty][tx] = Wk[(long)(e0 + ty) * DD + n0 + tx];
    *(f32x4*)&sq[ty][tx * 4] = *(const f32x4*)&Wq[(long)(e0 + ty) * DD + k0 + tx * 4];
    __syncthreads();
#pragma unroll
    for (int ee = 0; ee < 16; ++ee) {
      float kv = sk[ee][ty];
      f32x4 qv = *(const f32x4*)&sq[ee][tx * 4];
      acc[0] += kv * qv[0]; acc[1] += kv * qv[1];
      acc[2] += kv * qv[2]; acc[3] += kv * qv[3];
    }
    __syncthreads();
  }
  uint2 o;
  o.x = (unsigned)f2bf(acc[0]) | ((unsigned)f2bf(acc[1]) << 16);
  o.y = (unsigned)f2bf(acc[2]) | ((unsigned)f2bf(acc[3]) << 16);
  *(uint2*)&Gt[(long)(n0 + ty) * DD + k0 + tx * 4] = o;
}

// ---------------- 256x256 BT-GEMM, BK=32, ring-4, read-ahead pipeline ----------------
// EPI 0: bf16 out.  EPI 1: GELU(acc+bias) bf16.  EPI 2: acc+bias+resid -> fp32.
// EPI 3: acc+bias+resid -> bf16.

// One K-tile: counted vmcnt + barrier (RAW: stage(T+1) landed on all waves;
// WAR: all waves' reads of buf[T-1] lgkm-retired before stage(T+3) targets it),
// then ds_reads for T+1 + stage T+3, fence, 32 MFMA on T's resident frags.
#define TILE(T, RSLOT, SSLOT, CA, CB, NA, NB, DOREAD, DOSTAGE, VM4)            \
  {                                                                            \
    if (VM4) { asm volatile("s_waitcnt vmcnt(4)" ::: "memory"); }              \
    else     { asm volatile("s_waitcnt vmcnt(0)" ::: "memory"); }              \
    __builtin_amdgcn_s_barrier();                                              \
    asm volatile("" ::: "memory");                                             \
    if (DOREAD) {                                                              \
      const char* bn_ = ldsB + (RSLOT) * 32768;                                \
      _Pragma("unroll") for (int mi = 0; mi < 8; ++mi)                         \
        NA[mi] = *(const bf16x8*)(bn_ + aoff[mi]);                             \
      _Pragma("unroll") for (int nj = 0; nj < 4; ++nj)                         \
        NB[nj] = *(const bf16x8*)(bn_ + 16384 + boff[nj]);                     \
    }                                                                          \
    if (DOSTAGE) stage((T) + 3, ldsB + (SSLOT) * 32768);                       \
    __builtin_amdgcn_sched_barrier(0);                                         \
    __builtin_amdgcn_s_setprio(1);                                             \
    _Pragma("unroll") for (int mi = 0; mi < 8; ++mi)                           \
      _Pragma("unroll") for (int nj = 0; nj < 4; ++nj)                         \
        acc[mi][nj] = __builtin_amdgcn_mfma_f32_16x16x32_bf16(                 \
            CA[mi], CB[nj], acc[mi][nj], 0, 0, 0);                             \
    __builtin_amdgcn_s_setprio(0);                                             \
  }

template <int EPI>
__global__ void __launch_bounds__(512, 2) k_gemm256(
    const unsigned short* __restrict__ A,   // [M,1024] bf16
    const unsigned short* __restrict__ B,   // [N,1024] bf16 (BT layout)
    unsigned short* __restrict__ outb,
    float* __restrict__ outf,
    const float* __restrict__ bias,
    const unsigned short* __restrict__ resid,
    const int ntl2,                          // log2(n-tiles)
    const int cst) {                         // C col-stride (elems)
  __shared__ __align__(16) char ldsB[131072];  // 4 slots x (A 16K | B 16K)
  const int tid = threadIdx.x;
  const int lane = tid & 63;
  const int wid = tid >> 6;
  const int wm = wid >> 2, wn = wid & 3;

  // bijective XCD chunking; m-major so n-blocks sharing an A-strip co-reside
  const int nwg = gridDim.x;
  const int cpx = nwg >> 3;
  const int dd = blockIdx.x;
  const int lgc = (dd & 7) * cpx + (dd >> 3);
  const int mt = lgc >> ntl2;
  const int nt = lgc & ((1 << ntl2) - 1);
  const long m0 = (long)mt * 256;
  const int n0 = nt * 256;

  // ---- staging: thread covers 2 A-rows + 2 B-rows per tile (4 x 16B) ----
  const int srow = tid >> 2;          // 0..127
  const int scol = (tid & 3) * 16;    // byte col within 64-B K-slice
  const char* gA0 = (const char*)A + (m0 + srow) * 2048 + scol;
  const char* gA1 = gA0 + 128 * 2048;
  const char* gB0 = (const char*)B + ((long)n0 + srow) * 2048 + scol;
  const char* gB1 = gB0 + 128 * 2048;
  const int d0 = tid * 16;

  auto stage = [&](int kt, char* base) {
    const long ko = (long)kt << 6;
    gload_lds16(gA0 + ko, base + d0);
    gload_lds16(gA1 + ko, base + 8192 + d0);
    gload_lds16(gB0 + ko, base + 16384 + d0);
    gload_lds16(gB1 + ko, base + 24576 + d0);
  };

  // ---- fragment read offsets (linear, 64-B rows -> uniform bank load) ----
  const int la = lane & 15, lg = lane >> 4;
  int aoff[8], boff[4];
#pragma unroll
  for (int mi = 0; mi < 8; ++mi) aoff[mi] = (wm * 128 + mi * 16 + la) * 64 + lg * 16;
#pragma unroll
  for (int nj = 0; nj < 4; ++nj) boff[nj] = (wn * 64 + nj * 16 + la) * 64 + lg * 16;

  f32x4 acc[8][4];
#pragma unroll
  for (int mi = 0; mi < 8; ++mi)
#pragma unroll
    for (int nj = 0; nj < 4; ++nj) acc[mi][nj] = f32x4{0.f, 0.f, 0.f, 0.f};

  // ---- prologue: stage tiles 0,1,2; wait tile 0; load its frags ----
  stage(0, ldsB);
  stage(1, ldsB + 32768);
  stage(2, ldsB + 65536);
  asm volatile("s_waitcnt vmcnt(8)" ::: "memory");
  __builtin_amdgcn_s_barrier();
  asm volatile("" ::: "memory");

  bf16x8 a0[8], b0[4], a1[8], b1[4];
#pragma unroll
  for (int mi = 0; mi < 8; ++mi) a0[mi] = *(const bf16x8*)(ldsB + aoff[mi]);
#pragma unroll
  for (int nj = 0; nj < 4; ++nj) b0[nj] = *(const bf16x8*)(ldsB + 16384 + boff[nj]);

  // ---- main: tiles 0..27, ping-pong regs, slots period-4 ----
  for (int t0 = 0; t0 < 28; t0 += 4) {
    TILE(t0 + 0, 1, 3, a0, b0, a1, b1, true, true, true);
    TILE(t0 + 1, 2, 0, a1, b1, a0, b0, true, true, true);
    TILE(t0 + 2, 3, 1, a0, b0, a1, b1, true, true, true);
    TILE(t0 + 3, 0, 2, a1, b1, a0, b0, true, true, true);
  }
  // ---- tail: tiles 28..31 ----
  TILE(28, 1, 3, a0, b0, a1, b1, true, true, true);    // stages tile 31
  TILE(29, 2, 0, a1, b1, a0, b0, true, false, true);
  TILE(30, 3, 1, a0, b0, a1, b1, true, false, false);
  TILE(31, 0, 2, a1, b1, a0, b0, false, false, false);

  // ---- epilogue ----
  const long rbase = m0 + wm * 128 + (lane >> 4) * 4;
  const int cbase = n0 + wn * 64 + la;
#pragma unroll
  for (int mi = 0; mi < 8; ++mi) {
#pragma unroll
    for (int nj = 0; nj < 4; ++nj) {
      const int col = cbase + nj * 16;
      float bv = 0.f;
      if constexpr (EPI != 0) bv = bias[col];
#pragma unroll
      for (int t = 0; t < 4; ++t) {
        const long r = rbase + mi * 16 + t;
        float v = acc[mi][nj][t];
        if constexpr (EPI == 0) {
          outb[r * (long)cst + col] = f2bf(v);
        } else if constexpr (EPI == 1) {
          v += bv;
          v = 0.5f * v * (1.0f + erff(v * 0.70710678118654752f));
          outb[r * (long)cst + col] = f2bf(v);
        } else if constexpr (EPI == 2) {
          v += bv + bf2f(resid[r * (long)cst + col]);
          outf[r * (long)cst + col] = v;
        } else {
          v += bv + bf2f(resid[r * (long)cst + col]);
          outb[r * (long)cst + col] = f2bf(v);
        }
      }
    }
  }
}

// ---------------- attn + LN (uv interleaved [M][2048]) ----------------
__global__ void __launch_bounds__(256) k_attn_ln(
    const unsigned short* __restrict__ xb, const unsigned short* __restrict__ uv,
    unsigned short* __restrict__ yb, const int* __restrict__ mask,
    const float* __restrict__ att_g, const float* __restrict__ att_b) {
  const int b = blockIdx.x * 4 + (threadIdx.x >> 6);
  const int lane = threadIdx.x & 63;
  const long xbase = (long)b * 5120 + lane * 16;
  const long ubase = (long)b * 10240 + lane * 16;

  float xr[5][16];
  float sc[5];
#pragma unroll
  for (int l = 0; l < 5; ++l) {
    const unsigned short* xp = xb + xbase + l * 1024;
    const unsigned short* up = uv + ubase + l * 2048;
    unpack8(*(const uint4*)xp, xr[l]); unpack8(*(const uint4*)(xp + 8), xr[l] + 8);
    float uu[16];
    unpack8(*(const uint4*)up, uu); unpack8(*(const uint4*)(up + 8), uu + 8);
    float d = 0.f;
#pragma unroll
    for (int c = 0; c < 16; ++c) d += xr[l][c] * uu[c];
#pragma unroll
    for (int off = 32; off; off >>= 1) d += __shfl_xor(d, off);
    sc[l] = d * 0.03125f;
  }
  bool keep[5];
  float m = -1e30f;
#pragma unroll
  for (int l = 0; l < 5; ++l) {
    keep[l] = (mask[l] != 0);
    if (keep[l]) m = fmaxf(m, sc[l]);
  }
  float p[5], s = 0.f;
#pragma unroll
  for (int l = 0; l < 5; ++l) {
    p[l] = keep[l] ? __expf(sc[l] - m) : 0.f;
    s += p[l];
  }
  const float inv = 1.f / s;

  float gg[16], bb[16];
  {
    const float* gp = att_g + lane * 16;
    const float* bp = att_b + lane * 16;
#pragma unroll
    for (int q = 0; q < 4; ++q) {
      f32x4 gv = *(const f32x4*)(gp + q * 4);
      f32x4 bv = *(const f32x4*)(bp + q * 4);
#pragma unroll
      for (int c = 0; c < 4; ++c) { gg[q * 4 + c] = gv[c]; bb[q * 4 + c] = bv[c]; }
    }
  }

#pragma unroll
  for (int l = 0; l < 5; ++l) {
    const unsigned short* vp = uv + ubase + l * 2048 + 1024;
    float vv[16];
    unpack8(*(const uint4*)vp, vv); unpack8(*(const uint4*)(vp + 8), vv + 8);
    const float pl = p[l] * inv;
    float t[16], sm = 0.f, sq = 0.f;
#pragma unroll
    for (int c = 0; c < 16; ++c) {
      t[c] = pl * vv[c] + xr[l][c];
      sm += t[c];
      sq += t[c] * t[c];
    }
#pragma unroll
    for (int off = 32; off; off >>= 1) {
      sm += __shfl_xor(sm, off);
      sq += __shfl_xor(sq, off);
    }
    const float mu = sm * (1.f / 1024.f);
    const float var = sq * (1.f / 1024.f) - mu * mu;
    const float rs = rsqrtf(var + 1e-5f);
    unsigned short r[16];
#pragma unroll
    for (int c = 0; c < 16; ++c) r[c] = f2bf((t[c] - mu) * rs * gg[c] + bb[c]);
    uint4 o0, o1;
    o0.x = (unsigned)r[0] | ((unsigned)r[1] << 16);  o0.y = (unsigned)r[2] | ((unsigned)r[3] << 16);
    o0.z = (unsigned)r[4] | ((unsigned)r[5] << 16);  o0.w = (unsigned)r[6] | ((unsigned)r[7] << 16);
    o1.x = (unsigned)r[8] | ((unsigned)r[9] << 16);  o1.y = (unsigned)r[10] | ((unsigned)r[11] << 16);
    o1.z = (unsigned)r[12] | ((unsigned)r[13] << 16); o1.w = (unsigned)r[14] | ((unsigned)r[15] << 16);
    unsigned short* yp = yb + xbase + l * 1024;
    *(uint4*)yp = o0;
    *(uint4*)(yp + 8) = o1;
  }
}

// ---------------- final LN, bf16 z -> fp32 out ----------------
__global__ void __launch_bounds__(256) k_ln_final_bf(const unsigned short* __restrict__ zb,
                                                     float* __restrict__ out,
                                                     const float* __restrict__ g,
                                                     const float* __restrict__ bb) {
  const int lane = threadIdx.x & 63;
  const long row = (long)blockIdx.x * 4 + (threadIdx.x >> 6);
  const unsigned short* p = zb + row * DD + lane * 16;
  float t[16];
  unpack8(*(const uint4*)p, t);
  unpack8(*(const uint4*)(p + 8), t + 8);
  float sm = 0.f, sq = 0.f;
#pragma unroll
  for (int c = 0; c < 16; ++c) { sm += t[c]; sq += t[c] * t[c]; }
#pragma unroll
  for (int off = 32; off; off >>= 1) {
    sm += __shfl_xor(sm, off);
    sq += __shfl_xor(sq, off);
  }
  const float mu = sm * (1.f / 1024.f);
  const float var = sq * (1.f / 1024.f) - mu * mu;
  const float rs = rsqrtf(var + 1e-5f);
  float* op = out + row * DD + lane * 16;
  const float* gp = g + lane * 16;
  const float* bp = bb + lane * 16;
#pragma unroll
  for (int q = 0; q < 4; ++q) {
    f32x4 gv = *(const f32x4*)(gp + q * 4);
    f32x4 bv = *(const f32x4*)(bp + q * 4);
    f32x4 o;
#pragma unroll
    for (int c = 0; c < 4; ++c) o[c] = (t[q * 4 + c] - mu) * rs * gv[c] + bv[c];
    *(f32x4*)(op + q * 4) = o;
  }
}

// ---------------- final LN, fp32 z in-place (fallback, small ws) ----------------
__global__ void __launch_bounds__(256) k_ln_final(float* __restrict__ z,
                                                  const float* __restrict__ g,
                                                  const float* __restrict__ bb) {
  const int lane = threadIdx.x & 63;
  const long row = (long)blockIdx.x * 4 + (threadIdx.x >> 6);
  float* p = z + row * DD + lane * 16;
  f32x4 v[4];
  float sm = 0.f, sq = 0.f;
#pragma unroll
  for (int q = 0; q < 4; ++q) {
    v[q] = *(const f32x4*)(p + q * 4);
#pragma unroll
    for (int c = 0; c < 4; ++c) { sm += v[q][c]; sq += v[q][c] * v[q][c]; }
  }
#pragma unroll
  for (int off = 32; off; off >>= 1) {
    sm += __shfl_xor(sm, off);
    sq += __shfl_xor(sq, off);
  }
  const float mu = sm * (1.f / 1024.f);
  const float var = sq * (1.f / 1024.f) - mu * mu;
  const float rs = rsqrtf(var + 1e-5f);
  const float* gp = g + lane * 16;
  const float* bp = bb + lane * 16;
#pragma unroll
  for (int q = 0; q < 4; ++q) {
    f32x4 gv = *(const f32x4*)(gp + q * 4);
    f32x4 bv = *(const f32x4*)(bp + q * 4);
#pragma unroll
    for (int c = 0; c < 4; ++c) v[q][c] = (v[q][c] - mu) * rs * gv[c] + bv[c];
    *(f32x4*)(p + q * 4) = v[q];
  }
}

extern "C" void kernel_launch(void* const* d_in, const int* in_sizes, int n_in,
                              void* d_out, int out_size, void* d_ws, size_t ws_size,
                              hipStream_t stream) {
  const float* x     = (const float*)d_in[0];
  const int*   mask  = (const int*)d_in[1];
  const float* Wq    = (const float*)d_in[2];
  const float* Wk    = (const float*)d_in[3];
  const float* Wv    = (const float*)d_in[4];
  const float* W1    = (const float*)d_in[5];
  const float* b1    = (const float*)d_in[6];
  const float* W2    = (const float*)d_in[7];
  const float* b2    = (const float*)d_in[8];
  const float* att_g = (const float*)d_in[9];
  const float* att_b = (const float*)d_in[10];
  const float* ff_g  = (const float*)d_in[11];
  const float* ff_b  = (const float*)d_in[12];

  const long NE = NROWS * DD;
  unsigned short* xb   = (unsigned short*)d_ws;      // bf16 x, becomes y in place
  unsigned short* hb   = xb + NE;                    // GELU output
  unsigned short* Bcat = hb + NE;                    // [Gt ; Wv]  (2048 x 1024)
  unsigned short* W1b  = Bcat + 2L * DD * DD;
  unsigned short* W2b  = W1b + (long)DD * DD;
  unsigned short* zb   = W2b + (long)DD * DD;        // bf16 z (optional)

  const size_t need_zb = (size_t)(3L * NE + 4L * DD * DD) * 2;
  const bool use_zb = ws_size >= need_zb;

  unsigned short* uvb = (unsigned short*)d_out;      // [M][2048] bf16, exact fit
  float* outf = (float*)d_out;

  k_cvt_bf16<<<2048, 256, 0, stream>>>(x, xb, NE);
  k_cvt_bf16<<<512, 256, 0, stream>>>(Wv, Bcat + (long)DD * DD, (long)DD * DD);
  k_cvt_bf16<<<512, 256, 0, stream>>>(W1, W1b, (long)DD * DD);
  k_cvt_bf16<<<512, 256, 0, stream>>>(W2, W2b, (long)DD * DD);
  k_gt<<<dim3(16, 64), dim3(16, 16), 0, stream>>>(Wq, Wk, Bcat);

  // [u|v] = xb @ Bcat^T : M=81920, N=2048  -> 320*8 blocks
  k_gemm256<0><<<2560, 512, 0, stream>>>(xb, Bcat, uvb, nullptr, nullptr, nullptr, 3, 2048);
  k_attn_ln<<<4096, 256, 0, stream>>>(xb, uvb, xb, mask, att_g, att_b);
  // h = GELU(y @ W1^T + b1) : N=1024 -> 320*4 blocks
  k_gemm256<1><<<1280, 512, 0, stream>>>(xb, W1b, hb, nullptr, b1, nullptr, 2, 1024);
  if (use_zb) {
    // z = h @ W2^T + b2 + y -> bf16 zb, then LN -> fp32 d_out
    k_gemm256<3><<<1280, 512, 0, stream>>>(hb, W2b, zb, nullptr, b2, xb, 2, 1024);
    k_ln_final_bf<<<20480, 256, 0, stream>>>(zb, outf, ff_g, ff_b);
  } else {
    k_gemm256<2><<<1280, 512, 0, stream>>>(hb, W2b, nullptr, outf, b2, xb, 2, 1024);
    k_ln_final<<<20480, 256, 0, stream>>>(outf, ff_g, ff_b);
  }
}

// Round 5
// 1287.190 us; speedup vs baseline: 1.0141x; 1.0141x over previous
//
#include <hip/hip_runtime.h>
#include <hip/hip_bf16.h>
#include <cstdint>

// B=16384, L=5, D=1024.  M = 81920 rows.
// scores = x^T (Wq^T Wk) x  ->  Gt[n,k]; u = x@Gt^T; s = rowdot(u,x)/32.
// Pipeline:
//   k_cvt_bf16: x->xb ; Wv->Bcat[1024:2048] ; W1->W1b ; W2->W2b
//   k_gt:       Gt -> Bcat[0:1024]
//   k_gemm256<0>: [u|v] = xb @ Bcat^T  -> d_out as bf16 [M][2048]
//   k_attn_ln:  scores->softmax->attn, y = LN(attn+x) -> xb in place
//   k_gemm256<1>: h = GELU(y @ W1^T + b1) -> hb
//   k_gemm256<3>: z = h @ W2^T + b2 + y -> zb bf16 (ws)
//   k_ln_final_bf: LN(z)*ff_g+ff_b -> d_out fp32
//
// GEMM: 256x256 tile, BK=32, ring-4 LDS slots (128 KiB), read-ahead frag
// pipeline (ds_reads for t+1 into ping-pong regs + stage t+3 issued BEFORE
// tile t's 32 MFMAs; counted lgkmcnt drains reads under MFMA; one counted
// vmcnt(4)+barrier per tile).  XOR swizzle granule^=(row>>1)&3 on BOTH sides
// (pre-swizzled global source, linear LDS dest; swizzled frag reads) ->
// <=2-way bank aliasing (free).  Bijective XCD chunking, m-major.

typedef float f32x4 __attribute__((ext_vector_type(4)));
typedef __bf16 bf16x8 __attribute__((ext_vector_type(8)));

#define DD 1024
#define NROWS 81920L

__device__ __forceinline__ unsigned short f2bf(float f) {
  union { float f; unsigned u; } c; c.f = f;
  unsigned u = c.u;
  return (unsigned short)((u + 0x7FFFu + ((u >> 16) & 1u)) >> 16);  // RNE
}
__device__ __forceinline__ float bf2f(unsigned short b) {
  union { unsigned u; float f; } c; c.u = ((unsigned)b) << 16;
  return c.f;
}
__device__ __forceinline__ void unpack8(uint4 v, float* o) {
  o[0] = bf2f((unsigned short)(v.x & 0xffffu)); o[1] = bf2f((unsigned short)(v.x >> 16));
  o[2] = bf2f((unsigned short)(v.y & 0xffffu)); o[3] = bf2f((unsigned short)(v.y >> 16));
  o[4] = bf2f((unsigned short)(v.z & 0xffffu)); o[5] = bf2f((unsigned short)(v.z >> 16));
  o[6] = bf2f((unsigned short)(v.w & 0xffffu)); o[7] = bf2f((unsigned short)(v.w >> 16));
}
__device__ __forceinline__ void gload_lds16(const void* g, void* l) {
  __builtin_amdgcn_global_load_lds(
      (const __attribute__((address_space(1))) unsigned int*)g,
      (__attribute__((address_space(3))) unsigned int*)l, 16, 0, 0);
}

// ---------------- fp32 -> bf16 ----------------
__global__ void __launch_bounds__(256) k_cvt_bf16(const float* __restrict__ in,
                                                  unsigned short* __restrict__ out, long n) {
  long i = ((long)blockIdx.x * blockDim.x + threadIdx.x) * 8;
  long stride = (long)gridDim.x * blockDim.x * 8;
  for (; i < n; i += stride) {
    f32x4 a = *(const f32x4*)(in + i);
    f32x4 b = *(const f32x4*)(in + i + 4);
    uint4 o;
    o.x = (unsigned)f2bf(a[0]) | ((unsigned)f2bf(a[1]) << 16);
    o.y = (unsigned)f2bf(a[2]) | ((unsigned)f2bf(a[3]) << 16);
    o.z = (unsigned)f2bf(b[0]) | ((unsigned)f2bf(b[1]) << 16);
    o.w = (unsigned)f2bf(b[2]) | ((unsigned)f2bf(b[3]) << 16);
    *(uint4*)(out + i) = o;
  }
}

// ---------------- Gt[n,k] = sum_e Wk[e,n] * Wq[e,k] ----------------
__global__ void __launch_bounds__(256) k_gt(const float* __restrict__ Wq,
                                            const float* __restrict__ Wk,
                                            unsigned short* __restrict__ Gt) {
  __shared__ float sk[16][16];
  __shared__ float sq[16][64];
  const int tx = threadIdx.x, ty = threadIdx.y;
  const int n0 = blockIdx.y * 16;
  const int k0 = blockIdx.x * 64;
  float acc[4] = {0.f, 0.f, 0.f, 0.f};
  for (int e0 = 0; e0 < 1024; e0 += 16) {
    sk[ty][tx] = Wk[(long)(e0 + ty) * DD + n0 + tx];
    *(f32x4*)&sq[ty][tx * 4] = *(const f32x4*)&Wq[(long)(e0 + ty) * DD + k0 + tx * 4];
    __syncthreads();
#pragma unroll
    for (int ee = 0; ee < 16; ++ee) {
      float kv = sk[ee][ty];
      f32x4 qv = *(const f32x4*)&sq[ee][tx * 4];
      acc[0] += kv * qv[0]; acc[1] += kv * qv[1];
      acc[2] += kv * qv[2]; acc[3] += kv * qv[3];
    }
    __syncthreads();
  }
  uint2 o;
  o.x = (unsigned)f2bf(acc[0]) | ((unsigned)f2bf(acc[1]) << 16);
  o.y = (unsigned)f2bf(acc[2]) | ((unsigned)f2bf(acc[3]) << 16);
  *(uint2*)&Gt[(long)(n0 + ty) * DD + k0 + tx * 4] = o;
}

// ---------------- 256x256 BT-GEMM, BK=32, ring-4, read-ahead + swizzle ----------------
// EPI 0: bf16 out.  EPI 1: GELU(acc+bias) bf16.  EPI 2: acc+bias+resid -> fp32.
// EPI 3: acc+bias+resid -> bf16.

// One K-tile: counted vmcnt + barrier (RAW: stage(T+1) landed on all waves;
// WAR: all waves' reads of buf[T-1] retired before stage(T+3) targets it),
// then ds_reads for T+1 + stage T+3, fence, 32 MFMA on T's resident frags.
#define TILE(T, RSLOT, SSLOT, CA, CB, NA, NB, DOREAD, DOSTAGE, VM4)            \
  {                                                                            \
    if (VM4) { asm volatile("s_waitcnt vmcnt(4)" ::: "memory"); }              \
    else     { asm volatile("s_waitcnt vmcnt(0)" ::: "memory"); }              \
    __builtin_amdgcn_s_barrier();                                              \
    asm volatile("" ::: "memory");                                             \
    if (DOREAD) {                                                              \
      const char* bn_ = ldsB + (RSLOT) * 32768;                                \
      _Pragma("unroll") for (int mi = 0; mi < 8; ++mi)                         \
        NA[mi] = *(const bf16x8*)(bn_ + aoff[mi]);                             \
      _Pragma("unroll") for (int nj = 0; nj < 4; ++nj)                         \
        NB[nj] = *(const bf16x8*)(bn_ + 16384 + boff[nj]);                     \
    }                                                                          \
    if (DOSTAGE) stage((T) + 3, ldsB + (SSLOT) * 32768);                       \
    __builtin_amdgcn_sched_barrier(0);                                         \
    __builtin_amdgcn_s_setprio(1);                                             \
    _Pragma("unroll") for (int mi = 0; mi < 8; ++mi)                           \
      _Pragma("unroll") for (int nj = 0; nj < 4; ++nj)                         \
        acc[mi][nj] = __builtin_amdgcn_mfma_f32_16x16x32_bf16(                 \
            CA[mi], CB[nj], acc[mi][nj], 0, 0, 0);                             \
    __builtin_amdgcn_s_setprio(0);                                             \
  }

template <int EPI>
__global__ void __launch_bounds__(512, 2) k_gemm256(
    const unsigned short* __restrict__ A,   // [M,1024] bf16
    const unsigned short* __restrict__ B,   // [N,1024] bf16 (BT layout)
    unsigned short* __restrict__ outb,
    float* __restrict__ outf,
    const float* __restrict__ bias,
    const unsigned short* __restrict__ resid,
    const int ntl2,                          // log2(n-tiles)
    const int cst) {                         // C col-stride (elems)
  __shared__ __align__(16) char ldsB[131072];  // 4 slots x (A 16K | B 16K)
  const int tid = threadIdx.x;
  const int lane = tid & 63;
  const int wid = tid >> 6;
  const int wm = wid >> 2, wn = wid & 3;

  // bijective XCD chunking; m-major so n-blocks sharing an A-strip co-reside
  const int nwg = gridDim.x;
  const int cpx = nwg >> 3;
  const int dd = blockIdx.x;
  const int lgc = (dd & 7) * cpx + (dd >> 3);
  const int mt = lgc >> ntl2;
  const int nt = lgc & ((1 << ntl2) - 1);
  const long m0 = (long)mt * 256;
  const int n0 = nt * 256;

  // ---- staging: 2 A-rows + 2 B-rows per thread per tile (4 x 16B) ----
  // LDS dest linear: d0 = tid*16 (= row srow, granule sg). Global source
  // pre-swizzled: granule sg ^ ((srow>>1)&3). Rows +128 share the swizzle.
  const int srow = tid >> 2;          // 0..127
  const int oc = ((tid & 3) << 4) ^ (((srow >> 1) & 3) << 4);
  const char* gA0 = (const char*)A + (m0 + srow) * 2048 + oc;
  const char* gA1 = gA0 + 128 * 2048;
  const char* gB0 = (const char*)B + ((long)n0 + srow) * 2048 + oc;
  const char* gB1 = gB0 + 128 * 2048;
  const int d0 = tid * 16;

  auto stage = [&](int kt, char* base) {
    const long ko = (long)kt << 6;
    gload_lds16(gA0 + ko, base + d0);
    gload_lds16(gA1 + ko, base + 8192 + d0);
    gload_lds16(gB0 + ko, base + 16384 + d0);
    gload_lds16(gB1 + ko, base + 24576 + d0);
  };

  // ---- fragment read offsets (swizzled to match) ----
  const int la = lane & 15, lg = lane >> 4;
  const int cb = ((lg ^ ((la >> 1) & 3)) << 4);
  int aoff[8], boff[4];
#pragma unroll
  for (int mi = 0; mi < 8; ++mi) aoff[mi] = (wm * 128 + mi * 16 + la) * 64 + cb;
#pragma unroll
  for (int nj = 0; nj < 4; ++nj) boff[nj] = (wn * 64 + nj * 16 + la) * 64 + cb;

  f32x4 acc[8][4];
#pragma unroll
  for (int mi = 0; mi < 8; ++mi)
#pragma unroll
    for (int nj = 0; nj < 4; ++nj) acc[mi][nj] = f32x4{0.f, 0.f, 0.f, 0.f};

  // ---- prologue: stage tiles 0,1,2; wait tile 0; load its frags ----
  stage(0, ldsB);
  stage(1, ldsB + 32768);
  stage(2, ldsB + 65536);
  asm volatile("s_waitcnt vmcnt(8)" ::: "memory");
  __builtin_amdgcn_s_barrier();
  asm volatile("" ::: "memory");

  bf16x8 a0[8], b0[4], a1[8], b1[4];
#pragma unroll
  for (int mi = 0; mi < 8; ++mi) a0[mi] = *(const bf16x8*)(ldsB + aoff[mi]);
#pragma unroll
  for (int nj = 0; nj < 4; ++nj) b0[nj] = *(const bf16x8*)(ldsB + 16384 + boff[nj]);

  // ---- main: tiles 0..27, ping-pong regs, slots period-4 ----
  for (int t0 = 0; t0 < 28; t0 += 4) {
    TILE(t0 + 0, 1, 3, a0, b0, a1, b1, true, true, true);
    TILE(t0 + 1, 2, 0, a1, b1, a0, b0, true, true, true);
    TILE(t0 + 2, 3, 1, a0, b0, a1, b1, true, true, true);
    TILE(t0 + 3, 0, 2, a1, b1, a0, b0, true, true, true);
  }
  // ---- tail: tiles 28..31 ----
  TILE(28, 1, 3, a0, b0, a1, b1, true, true, true);    // stages tile 31
  TILE(29, 2, 0, a1, b1, a0, b0, true, false, true);
  TILE(30, 3, 1, a0, b0, a1, b1, true, false, false);
  TILE(31, 0, 2, a1, b1, a0, b0, false, false, false);

  // ---- epilogue ----
  const long rbase = m0 + wm * 128 + (lane >> 4) * 4;
  const int cbase = n0 + wn * 64 + la;
#pragma unroll
  for (int mi = 0; mi < 8; ++mi) {
#pragma unroll
    for (int nj = 0; nj < 4; ++nj) {
      const int col = cbase + nj * 16;
      float bv = 0.f;
      if constexpr (EPI != 0) bv = bias[col];
#pragma unroll
      for (int t = 0; t < 4; ++t) {
        const long r = rbase + mi * 16 + t;
        float v = acc[mi][nj][t];
        if constexpr (EPI == 0) {
          outb[r * (long)cst + col] = f2bf(v);
        } else if constexpr (EPI == 1) {
          v += bv;
          v = 0.5f * v * (1.0f + erff(v * 0.70710678118654752f));
          outb[r * (long)cst + col] = f2bf(v);
        } else if constexpr (EPI == 2) {
          v += bv + bf2f(resid[r * (long)cst + col]);
          outf[r * (long)cst + col] = v;
        } else {
          v += bv + bf2f(resid[r * (long)cst + col]);
          outb[r * (long)cst + col] = f2bf(v);
        }
      }
    }
  }
}

// ---------------- attn + LN (uv interleaved [M][2048]) ----------------
__global__ void __launch_bounds__(256) k_attn_ln(
    const unsigned short* __restrict__ xb, const unsigned short* __restrict__ uv,
    unsigned short* __restrict__ yb, const int* __restrict__ mask,
    const float* __restrict__ att_g, const float* __restrict__ att_b) {
  const int b = blockIdx.x * 4 + (threadIdx.x >> 6);
  const int lane = threadIdx.x & 63;
  const long xbase = (long)b * 5120 + lane * 16;
  const long ubase = (long)b * 10240 + lane * 16;

  float xr[5][16];
  float sc[5];
#pragma unroll
  for (int l = 0; l < 5; ++l) {
    const unsigned short* xp = xb + xbase + l * 1024;
    const unsigned short* up = uv + ubase + l * 2048;
    unpack8(*(const uint4*)xp, xr[l]); unpack8(*(const uint4*)(xp + 8), xr[l] + 8);
    float uu[16];
    unpack8(*(const uint4*)up, uu); unpack8(*(const uint4*)(up + 8), uu + 8);
    float d = 0.f;
#pragma unroll
    for (int c = 0; c < 16; ++c) d += xr[l][c] * uu[c];
#pragma unroll
    for (int off = 32; off; off >>= 1) d += __shfl_xor(d, off);
    sc[l] = d * 0.03125f;
  }
  bool keep[5];
  float m = -1e30f;
#pragma unroll
  for (int l = 0; l < 5; ++l) {
    keep[l] = (mask[l] != 0);
    if (keep[l]) m = fmaxf(m, sc[l]);
  }
  float p[5], s = 0.f;
#pragma unroll
  for (int l = 0; l < 5; ++l) {
    p[l] = keep[l] ? __expf(sc[l] - m) : 0.f;
    s += p[l];
  }
  const float inv = 1.f / s;

  float gg[16], bb[16];
  {
    const float* gp = att_g + lane * 16;
    const float* bp = att_b + lane * 16;
#pragma unroll
    for (int q = 0; q < 4; ++q) {
      f32x4 gv = *(const f32x4*)(gp + q * 4);
      f32x4 bv = *(const f32x4*)(bp + q * 4);
#pragma unroll
      for (int c = 0; c < 4; ++c) { gg[q * 4 + c] = gv[c]; bb[q * 4 + c] = bv[c]; }
    }
  }

#pragma unroll
  for (int l = 0; l < 5; ++l) {
    const unsigned short* vp = uv + ubase + l * 2048 + 1024;
    float vv[16];
    unpack8(*(const uint4*)vp, vv); unpack8(*(const uint4*)(vp + 8), vv + 8);
    const float pl = p[l] * inv;
    float t[16], sm = 0.f, sq = 0.f;
#pragma unroll
    for (int c = 0; c < 16; ++c) {
      t[c] = pl * vv[c] + xr[l][c];
      sm += t[c];
      sq += t[c] * t[c];
    }
#pragma unroll
    for (int off = 32; off; off >>= 1) {
      sm += __shfl_xor(sm, off);
      sq += __shfl_xor(sq, off);
    }
    const float mu = sm * (1.f / 1024.f);
    const float var = sq * (1.f / 1024.f) - mu * mu;
    const float rs = rsqrtf(var + 1e-5f);
    unsigned short r[16];
#pragma unroll
    for (int c = 0; c < 16; ++c) r[c] = f2bf((t[c] - mu) * rs * gg[c] + bb[c]);
    uint4 o0, o1;
    o0.x = (unsigned)r[0] | ((unsigned)r[1] << 16);  o0.y = (unsigned)r[2] | ((unsigned)r[3] << 16);
    o0.z = (unsigned)r[4] | ((unsigned)r[5] << 16);  o0.w = (unsigned)r[6] | ((unsigned)r[7] << 16);
    o1.x = (unsigned)r[8] | ((unsigned)r[9] << 16);  o1.y = (unsigned)r[10] | ((unsigned)r[11] << 16);
    o1.z = (unsigned)r[12] | ((unsigned)r[13] << 16); o1.w = (unsigned)r[14] | ((unsigned)r[15] << 16);
    unsigned short* yp = yb + xbase + l * 1024;
    *(uint4*)yp = o0;
    *(uint4*)(yp + 8) = o1;
  }
}

// ---------------- final LN, bf16 z -> fp32 out ----------------
__global__ void __launch_bounds__(256) k_ln_final_bf(const unsigned short* __restrict__ zb,
                                                     float* __restrict__ out,
                                                     const float* __restrict__ g,
                                                     const float* __restrict__ bb) {
  const int lane = threadIdx.x & 63;
  const long row = (long)blockIdx.x * 4 + (threadIdx.x >> 6);
  const unsigned short* p = zb + row * DD + lane * 16;
  float t[16];
  unpack8(*(const uint4*)p, t);
  unpack8(*(const uint4*)(p + 8), t + 8);
  float sm = 0.f, sq = 0.f;
#pragma unroll
  for (int c = 0; c < 16; ++c) { sm += t[c]; sq += t[c] * t[c]; }
#pragma unroll
  for (int off = 32; off; off >>= 1) {
    sm += __shfl_xor(sm, off);
    sq += __shfl_xor(sq, off);
  }
  const float mu = sm * (1.f / 1024.f);
  const float var = sq * (1.f / 1024.f) - mu * mu;
  const float rs = rsqrtf(var + 1e-5f);
  float* op = out + row * DD + lane * 16;
  const float* gp = g + lane * 16;
  const float* bp = bb + lane * 16;
#pragma unroll
  for (int q = 0; q < 4; ++q) {
    f32x4 gv = *(const f32x4*)(gp + q * 4);
    f32x4 bv = *(const f32x4*)(bp + q * 4);
    f32x4 o;
#pragma unroll
    for (int c = 0; c < 4; ++c) o[c] = (t[q * 4 + c] - mu) * rs * gv[c] + bv[c];
    *(f32x4*)(op + q * 4) = o;
  }
}

// ---------------- final LN, fp32 z in-place (fallback, small ws) ----------------
__global__ void __launch_bounds__(256) k_ln_final(float* __restrict__ z,
                                                  const float* __restrict__ g,
                                                  const float* __restrict__ bb) {
  const int lane = threadIdx.x & 63;
  const long row = (long)blockIdx.x * 4 + (threadIdx.x >> 6);
  float* p = z + row * DD + lane * 16;
  f32x4 v[4];
  float sm = 0.f, sq = 0.f;
#pragma unroll
  for (int q = 0; q < 4; ++q) {
    v[q] = *(const f32x4*)(p + q * 4);
#pragma unroll
    for (int c = 0; c < 4; ++c) { sm += v[q][c]; sq += v[q][c] * v[q][c]; }
  }
#pragma unroll
  for (int off = 32; off; off >>= 1) {
    sm += __shfl_xor(sm, off);
    sq += __shfl_xor(sq, off);
  }
  const float mu = sm * (1.f / 1024.f);
  const float var = sq * (1.f / 1024.f) - mu * mu;
  const float rs = rsqrtf(var + 1e-5f);
  const float* gp = g + lane * 16;
  const float* bp = bb + lane * 16;
#pragma unroll
  for (int q = 0; q < 4; ++q) {
    f32x4 gv = *(const f32x4*)(gp + q * 4);
    f32x4 bv = *(const f32x4*)(bp + q * 4);
#pragma unroll
    for (int c = 0; c < 4; ++c) v[q][c] = (v[q][c] - mu) * rs * gv[c] + bv[c];
    *(f32x4*)(p + q * 4) = v[q];
  }
}

extern "C" void kernel_launch(void* const* d_in, const int* in_sizes, int n_in,
                              void* d_out, int out_size, void* d_ws, size_t ws_size,
                              hipStream_t stream) {
  const float* x     = (const float*)d_in[0];
  const int*   mask  = (const int*)d_in[1];
  const float* Wq    = (const float*)d_in[2];
  const float* Wk    = (const float*)d_in[3];
  const float* Wv    = (const float*)d_in[4];
  const float* W1    = (const float*)d_in[5];
  const float* b1    = (const float*)d_in[6];
  const float* W2    = (const float*)d_in[7];
  const float* b2    = (const float*)d_in[8];
  const float* att_g = (const float*)d_in[9];
  const float* att_b = (const float*)d_in[10];
  const float* ff_g  = (const float*)d_in[11];
  const float* ff_b  = (const float*)d_in[12];

  const long NE = NROWS * DD;
  unsigned short* xb   = (unsigned short*)d_ws;      // bf16 x, becomes y in place
  unsigned short* hb   = xb + NE;                    // GELU output
  unsigned short* Bcat = hb + NE;                    // [Gt ; Wv]  (2048 x 1024)
  unsigned short* W1b  = Bcat + 2L * DD * DD;
  unsigned short* W2b  = W1b + (long)DD * DD;
  unsigned short* zb   = W2b + (long)DD * DD;        // bf16 z (optional)

  const size_t need_zb = (size_t)(3L * NE + 4L * DD * DD) * 2;
  const bool use_zb = ws_size >= need_zb;

  unsigned short* uvb = (unsigned short*)d_out;      // [M][2048] bf16, exact fit
  float* outf = (float*)d_out;

  k_cvt_bf16<<<2048, 256, 0, stream>>>(x, xb, NE);
  k_cvt_bf16<<<512, 256, 0, stream>>>(Wv, Bcat + (long)DD * DD, (long)DD * DD);
  k_cvt_bf16<<<512, 256, 0, stream>>>(W1, W1b, (long)DD * DD);
  k_cvt_bf16<<<512, 256, 0, stream>>>(W2, W2b, (long)DD * DD);
  k_gt<<<dim3(16, 64), dim3(16, 16), 0, stream>>>(Wq, Wk, Bcat);

  // [u|v] = xb @ Bcat^T : M=81920, N=2048  -> 320*8 blocks
  k_gemm256<0><<<2560, 512, 0, stream>>>(xb, Bcat, uvb, nullptr, nullptr, nullptr, 3, 2048);
  k_attn_ln<<<4096, 256, 0, stream>>>(xb, uvb, xb, mask, att_g, att_b);
  // h = GELU(y @ W1^T + b1) : N=1024 -> 320*4 blocks
  k_gemm256<1><<<1280, 512, 0, stream>>>(xb, W1b, hb, nullptr, b1, nullptr, 2, 1024);
  if (use_zb) {
    // z = h @ W2^T + b2 + y -> bf16 zb, then LN -> fp32 d_out
    k_gemm256<3><<<1280, 512, 0, stream>>>(hb, W2b, zb, nullptr, b2, xb, 2, 1024);
    k_ln_final_bf<<<20480, 256, 0, stream>>>(zb, outf, ff_g, ff_b);
  } else {
    k_gemm256<2><<<1280, 512, 0, stream>>>(hb, W2b, nullptr, outf, b2, xb, 2, 1024);
    k_ln_final<<<20480, 256, 0, stream>>>(outf, ff_g, ff_b);
  }
}

// Round 6
// 1246.900 us; speedup vs baseline: 1.0469x; 1.0323x over previous
//
#include <hip/hip_runtime.h>
#include <hip/hip_bf16.h>
#include <cstdint>

// B=16384, L=5, D=1024.  M = 81920 rows.
// scores = x^T (Wq^T Wk) x  ->  Gt[n,k]; u = x@Gt^T; s = rowdot(u,x)/32.
// Pipeline:
//   k_cvt_bf16: x->xb ; Wv->Bcat[1024:2048] ; W1->W1b ; W2->W2b
//   k_gt:       Gt -> Bcat[0:1024]
//   k_gemm256<0>: [u|v] = xb @ Bcat^T  -> d_out as bf16 [M][2048]
//   k_attn_ln:  scores->softmax->attn, y = LN(attn+x) -> xb in place
//   k_gemm256<1>: h = GELU(y @ W1^T + b1) -> hb
//   k_gemm256<3>: z = h @ W2^T + b2 + y -> zb bf16 (ws)
//   k_ln_final_bf: LN(z)*ff_g+ff_b -> d_out fp32
//
// GEMM: m201-style 8-phase schedule. BM=BN=256, BK=64, 8 waves (2Mx4N),
// dbuf-2 LDS (128 KiB), LDS layout per buffer: A[2 kk][256 rows][64B],
// B likewise at +32KB. 4 phases per K-step = (kk, mi-half) quadrants:
//   {ds_read 8|4 frags; stage 1 col-half of step s+1 (2 gload_lds); barrier;
//    lgkmcnt(0)+sched_barrier; setprio(1); 16 MFMA; setprio(0);
//    [vmcnt(4) at phases 2,4]; barrier}
// vmcnt(4) derivation: half needed next phase was staged 2 phases back; 4
// loads issued after it. Never vmcnt(0) in-loop; step 15 peeled to drain.
// XOR swizzle granule^=(row>>1)&3 both sides (R5-verified, 0 conflicts).

typedef float f32x4 __attribute__((ext_vector_type(4)));
typedef __bf16 bf16x8 __attribute__((ext_vector_type(8)));

#define DD 1024
#define NROWS 81920L

__device__ __forceinline__ unsigned short f2bf(float f) {
  union { float f; unsigned u; } c; c.f = f;
  unsigned u = c.u;
  return (unsigned short)((u + 0x7FFFu + ((u >> 16) & 1u)) >> 16);  // RNE
}
__device__ __forceinline__ float bf2f(unsigned short b) {
  union { unsigned u; float f; } c; c.u = ((unsigned)b) << 16;
  return c.f;
}
__device__ __forceinline__ void unpack8(uint4 v, float* o) {
  o[0] = bf2f((unsigned short)(v.x & 0xffffu)); o[1] = bf2f((unsigned short)(v.x >> 16));
  o[2] = bf2f((unsigned short)(v.y & 0xffffu)); o[3] = bf2f((unsigned short)(v.y >> 16));
  o[4] = bf2f((unsigned short)(v.z & 0xffffu)); o[5] = bf2f((unsigned short)(v.z >> 16));
  o[6] = bf2f((unsigned short)(v.w & 0xffffu)); o[7] = bf2f((unsigned short)(v.w >> 16));
}
__device__ __forceinline__ void gload_lds16(const void* g, void* l) {
  __builtin_amdgcn_global_load_lds(
      (const __attribute__((address_space(1))) unsigned int*)g,
      (__attribute__((address_space(3))) unsigned int*)l, 16, 0, 0);
}

// ---------------- fp32 -> bf16 ----------------
__global__ void __launch_bounds__(256) k_cvt_bf16(const float* __restrict__ in,
                                                  unsigned short* __restrict__ out, long n) {
  long i = ((long)blockIdx.x * blockDim.x + threadIdx.x) * 8;
  long stride = (long)gridDim.x * blockDim.x * 8;
  for (; i < n; i += stride) {
    f32x4 a = *(const f32x4*)(in + i);
    f32x4 b = *(const f32x4*)(in + i + 4);
    uint4 o;
    o.x = (unsigned)f2bf(a[0]) | ((unsigned)f2bf(a[1]) << 16);
    o.y = (unsigned)f2bf(a[2]) | ((unsigned)f2bf(a[3]) << 16);
    o.z = (unsigned)f2bf(b[0]) | ((unsigned)f2bf(b[1]) << 16);
    o.w = (unsigned)f2bf(b[2]) | ((unsigned)f2bf(b[3]) << 16);
    *(uint4*)(out + i) = o;
  }
}

// ---------------- Gt[n,k] = sum_e Wk[e,n] * Wq[e,k] ----------------
__global__ void __launch_bounds__(256) k_gt(const float* __restrict__ Wq,
                                            const float* __restrict__ Wk,
                                            unsigned short* __restrict__ Gt) {
  __shared__ float sk[16][16];
  __shared__ float sq[16][64];
  const int tx = threadIdx.x, ty = threadIdx.y;
  const int n0 = blockIdx.y * 16;
  const int k0 = blockIdx.x * 64;
  float acc[4] = {0.f, 0.f, 0.f, 0.f};
  for (int e0 = 0; e0 < 1024; e0 += 16) {
    sk[ty][tx] = Wk[(long)(e0 + ty) * DD + n0 + tx];
    *(f32x4*)&sq[ty][tx * 4] = *(const f32x4*)&Wq[(long)(e0 + ty) * DD + k0 + tx * 4];
    __syncthreads();
#pragma unroll
    for (int ee = 0; ee < 16; ++ee) {
      float kv = sk[ee][ty];
      f32x4 qv = *(const f32x4*)&sq[ee][tx * 4];
      acc[0] += kv * qv[0]; acc[1] += kv * qv[1];
      acc[2] += kv * qv[2]; acc[3] += kv * qv[3];
    }
    __syncthreads();
  }
  uint2 o;
  o.x = (unsigned)f2bf(acc[0]) | ((unsigned)f2bf(acc[1]) << 16);
  o.y = (unsigned)f2bf(acc[2]) | ((unsigned)f2bf(acc[3]) << 16);
  *(uint2*)&Gt[(long)(n0 + ty) * DD + k0 + tx * 4] = o;
}

// ---------------- 256x256 BT-GEMM, BK=64, dbuf-2, 8-phase ----------------
// EPI 0: bf16 out.  EPI 1: GELU(acc+bias) bf16.  EPI 2: acc+bias+resid -> fp32.
// EPI 3: acc+bias+resid -> bf16.

// TRAILV: 0 none, 1 vmcnt(4), 2 vmcnt(0)
#define PHASE(BUFC, KK, MIH, DOSTAGE, STG_ISB, STG_KK, SN, TRAILV)             \
  {                                                                            \
    const char* rb_ = (BUFC) + ((KK) << 14);                                   \
    if ((MIH) == 0) {                                                          \
      _Pragma("unroll") for (int j = 0; j < 4; ++j)                            \
        fb[j] = *(const bf16x8*)(rb_ + boff[j]);                               \
      _Pragma("unroll") for (int i = 0; i < 4; ++i)                            \
        fa[i] = *(const bf16x8*)(rb_ + aoff[i]);                               \
    } else {                                                                   \
      _Pragma("unroll") for (int i = 0; i < 4; ++i)                            \
        fa[i] = *(const bf16x8*)(rb_ + aoff[4 + i]);                           \
    }                                                                          \
    if (DOSTAGE) {                                                             \
      if (STG_ISB) stageB((SN), (STG_KK)); else stageA((SN), (STG_KK));        \
    }                                                                          \
    __builtin_amdgcn_s_barrier();                                              \
    asm volatile("s_waitcnt lgkmcnt(0)" ::: "memory");                         \
    __builtin_amdgcn_sched_barrier(0);                                         \
    __builtin_amdgcn_s_setprio(1);                                             \
    _Pragma("unroll") for (int i = 0; i < 4; ++i)                              \
      _Pragma("unroll") for (int j = 0; j < 4; ++j)                            \
        acc[(MIH) * 4 + i][j] = __builtin_amdgcn_mfma_f32_16x16x32_bf16(       \
            fa[i], fb[j], acc[(MIH) * 4 + i][j], 0, 0, 0);                     \
    __builtin_amdgcn_s_setprio(0);                                             \
    if ((TRAILV) == 1) asm volatile("s_waitcnt vmcnt(4)" ::: "memory");        \
    else if ((TRAILV) == 2) asm volatile("s_waitcnt vmcnt(0)" ::: "memory");   \
    __builtin_amdgcn_s_barrier();                                              \
    asm volatile("" ::: "memory");                                             \
  }

template <int EPI>
__global__ void __launch_bounds__(512, 2) k_gemm256(
    const unsigned short* __restrict__ A,   // [M,1024] bf16
    const unsigned short* __restrict__ B,   // [N,1024] bf16 (BT layout)
    unsigned short* __restrict__ outb,
    float* __restrict__ outf,
    const float* __restrict__ bias,
    const unsigned short* __restrict__ resid,
    const int ntl2,                          // log2(n-tiles)
    const int cst) {                         // C col-stride (elems)
  // buffer b at b*65536: A [kk][256 rows][64B] at +0, B likewise at +32768
  __shared__ __align__(16) char ldsB[131072];
  const int tid = threadIdx.x;
  const int lane = tid & 63;
  const int wid = tid >> 6;
  const int wm = wid >> 2, wn = wid & 3;

  // bijective XCD chunking; m-major so n-blocks sharing an A-strip co-reside
  const int nwg = gridDim.x;
  const int cpx = nwg >> 3;
  const int dd = blockIdx.x;
  const int lgc = (dd & 7) * cpx + (dd >> 3);
  const int mt = lgc >> ntl2;
  const int nt = lgc & ((1 << ntl2) - 1);
  const long m0 = (long)mt * 256;
  const int n0 = nt * 256;

  // ---- staging: one col-half (16 KB = 256 rows x 64B) = 2 gload_lds ----
  // LDS dest linear (tid*16, +8192); global source col pre-swizzled:
  // granule (tid&3) ^ ((row>>1)&3), row = tid>>2 (bits 1-2 invariant +128).
  const int q = tid >> 2;
  const int gcol = (((tid & 3) ^ ((q >> 1) & 3)) << 4);
  const char* gA = (const char*)A + (m0 + q) * 2048 + gcol;
  const char* gB = (const char*)B + ((long)n0 + q) * 2048 + gcol;
  const int ldst = tid * 16;

  auto stageA = [&](int s, int kk) {
    char* dst = ldsB + ((s & 1) << 16) + (kk << 14) + ldst;
    const char* src = gA + (long)s * 128 + (kk << 6);
    gload_lds16(src, dst);
    gload_lds16(src + 128 * 2048, dst + 8192);
  };
  auto stageB = [&](int s, int kk) {
    char* dst = ldsB + ((s & 1) << 16) + 32768 + (kk << 14) + ldst;
    const char* src = gB + (long)s * 128 + (kk << 6);
    gload_lds16(src, dst);
    gload_lds16(src + 128 * 2048, dst + 8192);
  };

  // ---- fragment read offsets (swizzled; rows of 64B within kk-region) ----
  const int la = lane & 15, lg = lane >> 4;
  const int cb = ((lg ^ ((la >> 1) & 3)) << 4);
  int aoff[8], boff[4];
#pragma unroll
  for (int mi = 0; mi < 8; ++mi) aoff[mi] = (wm * 128 + mi * 16 + la) * 64 + cb;
#pragma unroll
  for (int nj = 0; nj < 4; ++nj) boff[nj] = 32768 + (wn * 64 + nj * 16 + la) * 64 + cb;

  f32x4 acc[8][4];
#pragma unroll
  for (int mi = 0; mi < 8; ++mi)
#pragma unroll
    for (int nj = 0; nj < 4; ++nj) acc[mi][nj] = f32x4{0.f, 0.f, 0.f, 0.f};

  bf16x8 fa[4], fb[4];

  // ---- prologue: stage step 0 (A-k0, B-k0, A-k1, B-k1); oldest 4 = k0 ----
  stageA(0, 0); stageB(0, 0); stageA(0, 1); stageB(0, 1);
  asm volatile("s_waitcnt vmcnt(4)" ::: "memory");
  __builtin_amdgcn_s_barrier();
  asm volatile("" ::: "memory");

  // ---- main loop: steps 0..14, stage step s+1 one col-half per phase ----
  for (int s = 0; s < 15; ++s) {
    const int sn = s + 1;
    char* bufc = ldsB + ((s & 1) << 16);
    PHASE(bufc, 0, 0, true, false, 0, sn, 0);  // reads kk0; stage A-k0(s+1)
    PHASE(bufc, 0, 1, true, true,  0, sn, 1);  // stage B-k0(s+1); vmcnt(4)
    PHASE(bufc, 1, 0, true, false, 1, sn, 0);  // reads kk1; stage A-k1(s+1)
    PHASE(bufc, 1, 1, true, true,  1, sn, 1);  // stage B-k1(s+1); vmcnt(4)
  }
  // ---- peeled step 15: no staging; drain before kk1 reads ----
  {
    char* bufc = ldsB + ((15 & 1) << 16);
    PHASE(bufc, 0, 0, false, false, 0, 16, 0);
    PHASE(bufc, 0, 1, false, false, 0, 16, 2);  // vmcnt(0): A-k1/B-k1 landed
    PHASE(bufc, 1, 0, false, false, 1, 16, 0);
    PHASE(bufc, 1, 1, false, false, 1, 16, 0);
  }

  // ---- epilogue ----
  const long rbase = m0 + wm * 128 + (lane >> 4) * 4;
  const int cbase = n0 + wn * 64 + la;
#pragma unroll
  for (int mi = 0; mi < 8; ++mi) {
#pragma unroll
    for (int nj = 0; nj < 4; ++nj) {
      const int col = cbase + nj * 16;
      float bv = 0.f;
      if constexpr (EPI != 0) bv = bias[col];
#pragma unroll
      for (int t = 0; t < 4; ++t) {
        const long r = rbase + mi * 16 + t;
        float v = acc[mi][nj][t];
        if constexpr (EPI == 0) {
          outb[r * (long)cst + col] = f2bf(v);
        } else if constexpr (EPI == 1) {
          v += bv;
          v = 0.5f * v * (1.0f + erff(v * 0.70710678118654752f));
          outb[r * (long)cst + col] = f2bf(v);
        } else if constexpr (EPI == 2) {
          v += bv + bf2f(resid[r * (long)cst + col]);
          outf[r * (long)cst + col] = v;
        } else {
          v += bv + bf2f(resid[r * (long)cst + col]);
          outb[r * (long)cst + col] = f2bf(v);
        }
      }
    }
  }
}

// ---------------- attn + LN (uv interleaved [M][2048]) ----------------
__global__ void __launch_bounds__(256) k_attn_ln(
    const unsigned short* __restrict__ xb, const unsigned short* __restrict__ uv,
    unsigned short* __restrict__ yb, const int* __restrict__ mask,
    const float* __restrict__ att_g, const float* __restrict__ att_b) {
  const int b = blockIdx.x * 4 + (threadIdx.x >> 6);
  const int lane = threadIdx.x & 63;
  const long xbase = (long)b * 5120 + lane * 16;
  const long ubase = (long)b * 10240 + lane * 16;

  float xr[5][16];
  float sc[5];
#pragma unroll
  for (int l = 0; l < 5; ++l) {
    const unsigned short* xp = xb + xbase + l * 1024;
    const unsigned short* up = uv + ubase + l * 2048;
    unpack8(*(const uint4*)xp, xr[l]); unpack8(*(const uint4*)(xp + 8), xr[l] + 8);
    float uu[16];
    unpack8(*(const uint4*)up, uu); unpack8(*(const uint4*)(up + 8), uu + 8);
    float d = 0.f;
#pragma unroll
    for (int c = 0; c < 16; ++c) d += xr[l][c] * uu[c];
#pragma unroll
    for (int off = 32; off; off >>= 1) d += __shfl_xor(d, off);
    sc[l] = d * 0.03125f;
  }
  bool keep[5];
  float m = -1e30f;
#pragma unroll
  for (int l = 0; l < 5; ++l) {
    keep[l] = (mask[l] != 0);
    if (keep[l]) m = fmaxf(m, sc[l]);
  }
  float p[5], s = 0.f;
#pragma unroll
  for (int l = 0; l < 5; ++l) {
    p[l] = keep[l] ? __expf(sc[l] - m) : 0.f;
    s += p[l];
  }
  const float inv = 1.f / s;

  float gg[16], bb[16];
  {
    const float* gp = att_g + lane * 16;
    const float* bp = att_b + lane * 16;
#pragma unroll
    for (int q = 0; q < 4; ++q) {
      f32x4 gv = *(const f32x4*)(gp + q * 4);
      f32x4 bv = *(const f32x4*)(bp + q * 4);
#pragma unroll
      for (int c = 0; c < 4; ++c) { gg[q * 4 + c] = gv[c]; bb[q * 4 + c] = bv[c]; }
    }
  }

#pragma unroll
  for (int l = 0; l < 5; ++l) {
    const unsigned short* vp = uv + ubase + l * 2048 + 1024;
    float vv[16];
    unpack8(*(const uint4*)vp, vv); unpack8(*(const uint4*)(vp + 8), vv + 8);
    const float pl = p[l] * inv;
    float t[16], sm = 0.f, sq = 0.f;
#pragma unroll
    for (int c = 0; c < 16; ++c) {
      t[c] = pl * vv[c] + xr[l][c];
      sm += t[c];
      sq += t[c] * t[c];
    }
#pragma unroll
    for (int off = 32; off; off >>= 1) {
      sm += __shfl_xor(sm, off);
      sq += __shfl_xor(sq, off);
    }
    const float mu = sm * (1.f / 1024.f);
    const float var = sq * (1.f / 1024.f) - mu * mu;
    const float rs = rsqrtf(var + 1e-5f);
    unsigned short r[16];
#pragma unroll
    for (int c = 0; c < 16; ++c) r[c] = f2bf((t[c] - mu) * rs * gg[c] + bb[c]);
    uint4 o0, o1;
    o0.x = (unsigned)r[0] | ((unsigned)r[1] << 16);  o0.y = (unsigned)r[2] | ((unsigned)r[3] << 16);
    o0.z = (unsigned)r[4] | ((unsigned)r[5] << 16);  o0.w = (unsigned)r[6] | ((unsigned)r[7] << 16);
    o1.x = (unsigned)r[8] | ((unsigned)r[9] << 16);  o1.y = (unsigned)r[10] | ((unsigned)r[11] << 16);
    o1.z = (unsigned)r[12] | ((unsigned)r[13] << 16); o1.w = (unsigned)r[14] | ((unsigned)r[15] << 16);
    unsigned short* yp = yb + xbase + l * 1024;
    *(uint4*)yp = o0;
    *(uint4*)(yp + 8) = o1;
  }
}

// ---------------- final LN, bf16 z -> fp32 out ----------------
__global__ void __launch_bounds__(256) k_ln_final_bf(const unsigned short* __restrict__ zb,
                                                     float* __restrict__ out,
                                                     const float* __restrict__ g,
                                                     const float* __restrict__ bb) {
  const int lane = threadIdx.x & 63;
  const long row = (long)blockIdx.x * 4 + (threadIdx.x >> 6);
  const unsigned short* p = zb + row * DD + lane * 16;
  float t[16];
  unpack8(*(const uint4*)p, t);
  unpack8(*(const uint4*)(p + 8), t + 8);
  float sm = 0.f, sq = 0.f;
#pragma unroll
  for (int c = 0; c < 16; ++c) { sm += t[c]; sq += t[c] * t[c]; }
#pragma unroll
  for (int off = 32; off; off >>= 1) {
    sm += __shfl_xor(sm, off);
    sq += __shfl_xor(sq, off);
  }
  const float mu = sm * (1.f / 1024.f);
  const float var = sq * (1.f / 1024.f) - mu * mu;
  const float rs = rsqrtf(var + 1e-5f);
  float* op = out + row * DD + lane * 16;
  const float* gp = g + lane * 16;
  const float* bp = bb + lane * 16;
#pragma unroll
  for (int q = 0; q < 4; ++q) {
    f32x4 gv = *(const f32x4*)(gp + q * 4);
    f32x4 bv = *(const f32x4*)(bp + q * 4);
    f32x4 o;
#pragma unroll
    for (int c = 0; c < 4; ++c) o[c] = (t[q * 4 + c] - mu) * rs * gv[c] + bv[c];
    *(f32x4*)(op + q * 4) = o;
  }
}

// ---------------- final LN, fp32 z in-place (fallback, small ws) ----------------
__global__ void __launch_bounds__(256) k_ln_final(float* __restrict__ z,
                                                  const float* __restrict__ g,
                                                  const float* __restrict__ bb) {
  const int lane = threadIdx.x & 63;
  const long row = (long)blockIdx.x * 4 + (threadIdx.x >> 6);
  float* p = z + row * DD + lane * 16;
  f32x4 v[4];
  float sm = 0.f, sq = 0.f;
#pragma unroll
  for (int q = 0; q < 4; ++q) {
    v[q] = *(const f32x4*)(p + q * 4);
#pragma unroll
    for (int c = 0; c < 4; ++c) { sm += v[q][c]; sq += v[q][c] * v[q][c]; }
  }
#pragma unroll
  for (int off = 32; off; off >>= 1) {
    sm += __shfl_xor(sm, off);
    sq += __shfl_xor(sq, off);
  }
  const float mu = sm * (1.f / 1024.f);
  const float var = sq * (1.f / 1024.f) - mu * mu;
  const float rs = rsqrtf(var + 1e-5f);
  const float* gp = g + lane * 16;
  const float* bp = bb + lane * 16;
#pragma unroll
  for (int q = 0; q < 4; ++q) {
    f32x4 gv = *(const f32x4*)(gp + q * 4);
    f32x4 bv = *(const f32x4*)(bp + q * 4);
#pragma unroll
    for (int c = 0; c < 4; ++c) v[q][c] = (v[q][c] - mu) * rs * gv[c] + bv[c];
    *(f32x4*)(p + q * 4) = v[q];
  }
}

extern "C" void kernel_launch(void* const* d_in, const int* in_sizes, int n_in,
                              void* d_out, int out_size, void* d_ws, size_t ws_size,
                              hipStream_t stream) {
  const float* x     = (const float*)d_in[0];
  const int*   mask  = (const int*)d_in[1];
  const float* Wq    = (const float*)d_in[2];
  const float* Wk    = (const float*)d_in[3];
  const float* Wv    = (const float*)d_in[4];
  const float* W1    = (const float*)d_in[5];
  const float* b1    = (const float*)d_in[6];
  const float* W2    = (const float*)d_in[7];
  const float* b2    = (const float*)d_in[8];
  const float* att_g = (const float*)d_in[9];
  const float* att_b = (const float*)d_in[10];
  const float* ff_g  = (const float*)d_in[11];
  const float* ff_b  = (const float*)d_in[12];

  const long NE = NROWS * DD;
  unsigned short* xb   = (unsigned short*)d_ws;      // bf16 x, becomes y in place
  unsigned short* hb   = xb + NE;                    // GELU output
  unsigned short* Bcat = hb + NE;                    // [Gt ; Wv]  (2048 x 1024)
  unsigned short* W1b  = Bcat + 2L * DD * DD;
  unsigned short* W2b  = W1b + (long)DD * DD;
  unsigned short* zb   = W2b + (long)DD * DD;        // bf16 z (optional)

  const size_t need_zb = (size_t)(3L * NE + 4L * DD * DD) * 2;
  const bool use_zb = ws_size >= need_zb;

  unsigned short* uvb = (unsigned short*)d_out;      // [M][2048] bf16, exact fit
  float* outf = (float*)d_out;

  k_cvt_bf16<<<2048, 256, 0, stream>>>(x, xb, NE);
  k_cvt_bf16<<<512, 256, 0, stream>>>(Wv, Bcat + (long)DD * DD, (long)DD * DD);
  k_cvt_bf16<<<512, 256, 0, stream>>>(W1, W1b, (long)DD * DD);
  k_cvt_bf16<<<512, 256, 0, stream>>>(W2, W2b, (long)DD * DD);
  k_gt<<<dim3(16, 64), dim3(16, 16), 0, stream>>>(Wq, Wk, Bcat);

  // [u|v] = xb @ Bcat^T : M=81920, N=2048  -> 320*8 blocks
  k_gemm256<0><<<2560, 512, 0, stream>>>(xb, Bcat, uvb, nullptr, nullptr, nullptr, 3, 2048);
  k_attn_ln<<<4096, 256, 0, stream>>>(xb, uvb, xb, mask, att_g, att_b);
  // h = GELU(y @ W1^T + b1) : N=1024 -> 320*4 blocks
  k_gemm256<1><<<1280, 512, 0, stream>>>(xb, W1b, hb, nullptr, b1, nullptr, 2, 1024);
  if (use_zb) {
    // z = h @ W2^T + b2 + y -> bf16 zb, then LN -> fp32 d_out
    k_gemm256<3><<<1280, 512, 0, stream>>>(hb, W2b, zb, nullptr, b2, xb, 2, 1024);
    k_ln_final_bf<<<20480, 256, 0, stream>>>(zb, outf, ff_g, ff_b);
  } else {
    k_gemm256<2><<<1280, 512, 0, stream>>>(hb, W2b, nullptr, outf, b2, xb, 2, 1024);
    k_ln_final<<<20480, 256, 0, stream>>>(outf, ff_g, ff_b);
  }
}